// Round 5
// baseline (990.996 us; speedup 1.0000x reference)
//
#include <hip/hip_runtime.h>
#include <math.h>

#define HID 2048
#define NH 16
#define HD 128
#define INTERD 8192
#define SEQL 2048
#define NBATCH 2
#define NTOK (NBATCH*SEQL)

typedef float f32x4 __attribute__((ext_vector_type(4)));
typedef __bf16 bfx8 __attribute__((ext_vector_type(8)));

__device__ __forceinline__ float bf2f(unsigned short u){
  union { float f; unsigned v; } c; c.v = ((unsigned)u)<<16; return c.f;
}
__device__ __forceinline__ unsigned short f2bf(float f){
  union { float f; unsigned v; } c; c.f = f;
  unsigned r = c.v + 0x7FFFu + ((c.v>>16)&1u);   // RNE
  return (unsigned short)(r>>16);
}

// async global->LDS, 16B/lane; LDS dest = wave-uniform base + lane*16 (proven r3/r4).
__device__ __forceinline__ void gll16(const unsigned short* g, void* l){
  __builtin_amdgcn_global_load_lds(
      (const __attribute__((address_space(1))) unsigned int*)(size_t)(const void*)g,
      (__attribute__((address_space(3))) unsigned int*)(unsigned int)(size_t)l,
      16, 0, 0);
}

__global__ void k_sentinel(float* out){ out[0] = 1.0e9f; }

// ---------------- fp32 -> bf16 conversion (weights) ----------------
__global__ __launch_bounds__(256) void k_cvt(const float* __restrict__ in,
                                             unsigned short* __restrict__ out, int n4){
  int i = blockIdx.x*256 + threadIdx.x;
  if(i >= n4) return;
  float4 v = reinterpret_cast<const float4*>(in)[i];
  ushort4 o;
  o.x = f2bf(v.x); o.y = f2bf(v.y); o.z = f2bf(v.z); o.w = f2bf(v.w);
  reinterpret_cast<ushort4*>(out)[i] = o;
}

// ---------------- RMSNorm (fp32 in) -> bf16 out ----------------
__global__ __launch_bounds__(256) void k_rmsnorm(const float* __restrict__ x,
                                                 const float* __restrict__ w,
                                                 unsigned short* __restrict__ out){
  int row = blockIdx.x, t = threadIdx.x;
  const float4* xr = reinterpret_cast<const float4*>(x + (size_t)row*HID);
  float4 a = xr[2*t], b = xr[2*t+1];
  float ss = a.x*a.x+a.y*a.y+a.z*a.z+a.w*a.w + b.x*b.x+b.y*b.y+b.z*b.z+b.w*b.w;
  #pragma unroll
  for(int o=1;o<64;o<<=1) ss += __shfl_xor(ss, o);
  __shared__ float red[4];
  if((t&63)==0) red[t>>6] = ss;
  __syncthreads();
  float sc = rsqrtf((red[0]+red[1]+red[2]+red[3])*(1.0f/HID) + 1e-6f);
  const float4* wr = reinterpret_cast<const float4*>(w);
  float4 wa = wr[2*t], wb = wr[2*t+1];
  ushort4 o1, o2;
  o1.x=f2bf(a.x*sc*wa.x); o1.y=f2bf(a.y*sc*wa.y); o1.z=f2bf(a.z*sc*wa.z); o1.w=f2bf(a.w*sc*wa.w);
  o2.x=f2bf(b.x*sc*wb.x); o2.y=f2bf(b.y*sc*wb.y); o2.z=f2bf(b.z*sc*wb.z); o2.w=f2bf(b.w*sc*wb.w);
  ushort4* orow = reinterpret_cast<ushort4*>(out + (size_t)row*HID);
  orow[2*t] = o1; orow[2*t+1] = o2;
}

// ---------------- RoPE tables ----------------
__global__ void k_ropetab(float* __restrict__ cs, float* __restrict__ sn){
  int s = blockIdx.x, j = threadIdx.x;   // 64 threads
  float invf = powf(10000.0f, -(float)j*(1.0f/64.0f));
  float ang = (float)s * invf;
  float c, si;
  sincosf(ang, &si, &c);
  cs[s*64+j] = c; sn[s*64+j] = si;
}

// ---------------- RoPE apply in-place on bf16 [tok][ld] at head offset ----------------
__global__ __launch_bounds__(256) void k_rope(unsigned short* qk, int ld,
                                              const float* __restrict__ cs,
                                              const float* __restrict__ sn, float scale){
  int gid = blockIdx.x*256 + threadIdx.x;
  int j = gid & 63;
  int rh = gid >> 6;               // tok*NH + h
  int tok = rh >> 4, h = rh & 15;
  int s = tok & (SEQL-1);
  unsigned short* base = qk + (size_t)tok*ld + h*HD;
  float c = cs[s*64+j], sv = sn[s*64+j];
  float x1 = bf2f(base[j]), x2 = bf2f(base[j+64]);
  base[j]    = f2bf((x1*c - x2*sv)*scale);
  base[j+64] = f2bf((x2*c + x1*sv)*scale);
}

// ---------------- V transpose: VT[b,h,d,s] <- V[tok][ld] (bf16) ----------------
__global__ __launch_bounds__(256) void k_transpose_v(const unsigned short* __restrict__ V,
                                                     int ld,
                                                     unsigned short* __restrict__ VT){
  __shared__ unsigned short T[64*136];
  int bid = blockIdx.x;
  int sb = bid & 31, h = (bid>>5) & 15, b = bid>>9;
  int t = threadIdx.x;
  int s0 = sb<<6;
  int sl = t>>2, dc = (t&3)<<5;
  const unsigned short* src = V + (size_t)(b*SEQL + s0 + sl)*ld + h*HD + dc;
  #pragma unroll
  for(int p=0;p<4;p++){
    bfx8 v = *reinterpret_cast<const bfx8*>(src + p*8);
    *reinterpret_cast<bfx8*>(&T[sl*136 + dc + p*8]) = v;
  }
  __syncthreads();
  int d = t>>1, sh = (t&1)<<5;
  unsigned short* dst = VT + ((size_t)((b*NH + h)*HD + d))*SEQL + s0 + sh;
  #pragma unroll
  for(int p=0;p<4;p++){
    union { bfx8 v; unsigned short u[8]; } o;
    #pragma unroll
    for(int j=0;j<8;j++) o.u[j] = T[(sh + p*8 + j)*136 + d];
    *reinterpret_cast<bfx8*>(dst + p*8) = o.v;
  }
}

// ==================== GEMM: C[M,N] = A[M,K]*W[N,K]^T, m201-geometry pipeline ==========
// BM=BN=256, BK=32; 512 thr = 8 waves (2M x 4N), wave-tile 128x64 (8x4 16x16 frags).
// Triple-buffered LDS (3 x 32KB), prefetch distance 2 K-tiles, counted vmcnt(4)/K-tile.
// 2 phases/K-tile: P0 {8 ds_read || 2 gll; bar; lgkm0; 16 MFMA; bar}
//                  P1 {4 ds_read || 2 gll; bar; lgkm0; 16 MFMA; vmcnt(4); bar}.
// LDS tile layout: [128 row-pairs][8 chunks of 16B], chunk ^= (rp&7) via pre-swizzled
// gll source (both-sides involution, rule #21; proven 0-conflict family r3/r4).
// EPI 0: bf16.  EPI 1: fp32 = resid + acc.  EPI 2: bf16 = silu(gbuf)*acc.
#define GTILE 32768
template<int EPI>
__global__ __launch_bounds__(512, 2) void k_gemm(const unsigned short* __restrict__ A,
                                                 const unsigned short* __restrict__ W,
                                                 void* out, const float* __restrict__ resid,
                                                 const unsigned short* gbuf,
                                                 int M, int N, int K){
  __shared__ char lds[3*GTILE];            // per tile: A 16KB | B 16KB
  int nwg = gridDim.x;
  int bid = blockIdx.x;
  bid = (bid & 7)*(nwg>>3) + (bid>>3);     // XCD-aware swizzle (all grids %8==0)
  int nbn = N >> 8;
  int bm0 = (bid / nbn) << 8, bn0 = (bid % nbn) << 8;
  int t = threadIdx.x, w = t>>6, l = t&63, lr = l&15, lg = l>>4;
  int wm = w>>2, wn = w&3;
  int nt = K >> 5;

  // staging constants: lane l stages slot (l&7) of row-pair w*8 + (l>>3)
  int c    = (l&7) ^ (l>>3);               // logical chunk stored at this lane's slot
  int rowb = 2*((w<<3)+(l>>3)) + (c>>2);   // source row within 128-row half
  int kcof = (c&3)<<3;                     // source k-offset (elements)
  // read constants
  int rsw = (((((lr&1)<<2)|lg) ^ ((lr>>1)&7)) << 4);
  int rpb = lr>>1;

  f32x4 z = {0.f,0.f,0.f,0.f};
  f32x4 acc[8][4];
  #pragma unroll
  for(int i=0;i<8;i++){ acc[i][0]=z; acc[i][1]=z; acc[i][2]=z; acc[i][3]=z; }

  // issue j in {0,1} covers rows j*128..j*128+127 of the 256-row side-tile
  #define STAGE_A(bb, j, kk) \
    gll16(A + (size_t)(bm0 + (j)*128 + rowb)*K + (kk) + kcof, \
          (char*)(bb) + ((j)*64 + (w<<3))*128)
  #define STAGE_B(bb, j, kk) \
    gll16(W + (size_t)(bn0 + (j)*128 + rowb)*K + (kk) + kcof, \
          (char*)(bb) + 16384 + ((j)*64 + (w<<3))*128)

  // prologue: stage tiles 0,1 (8 gll/thread); drain tile 0, keep tile 1 in flight
  STAGE_A(lds,0,0); STAGE_A(lds,1,0); STAGE_B(lds,0,0); STAGE_B(lds,1,0);
  STAGE_A(lds+GTILE,0,32); STAGE_A(lds+GTILE,1,32);
  STAGE_B(lds+GTILE,0,32); STAGE_B(lds+GTILE,1,32);
  asm volatile("s_waitcnt vmcnt(4)" ::: "memory");
  __builtin_amdgcn_s_barrier();

  int cur = 0;
  for(int kt=0; kt<nt; ++kt){
    int pf = cur+2; if(pf>=3) pf-=3;       // prefetch buffer (its last reader was kt-1)
    int kp = kt+2; if(kp>=nt) kp = 0;      // wrap: stages unused-but-valid data
    int kpk = kp<<5;
    const char* Ac = lds + cur*GTILE;
    const char* Bc = Ac + 16384;
    char* Pb = lds + pf*GTILE;

    // ---------- P0: af[0..3] + bfr[0..3]; MFMA upper half ----------
    bfx8 af[4], bfr[4];
    #pragma unroll
    for(int fm=0;fm<4;fm++)
      af[fm] = *reinterpret_cast<const bfx8*>(Ac + (wm*64 + fm*8 + rpb)*128 + rsw);
    #pragma unroll
    for(int fn=0;fn<4;fn++)
      bfr[fn] = *reinterpret_cast<const bfx8*>(Bc + (wn*32 + fn*8 + rpb)*128 + rsw);
    STAGE_A(Pb,0,kpk); STAGE_A(Pb,1,kpk);
    __builtin_amdgcn_s_barrier();
    asm volatile("s_waitcnt lgkmcnt(0)" ::: "memory");
    __builtin_amdgcn_sched_barrier(0);
    __builtin_amdgcn_s_setprio(1);
    #pragma unroll
    for(int fm=0;fm<4;fm++)
      #pragma unroll
      for(int fn=0;fn<4;fn++)
        acc[fm][fn] = __builtin_amdgcn_mfma_f32_16x16x32_bf16(af[fm], bfr[fn], acc[fm][fn], 0,0,0);
    __builtin_amdgcn_s_setprio(0);
    __builtin_amdgcn_s_barrier();

    // ---------- P1: af[4..7]; MFMA lower half ----------
    bfx8 ag[4];
    #pragma unroll
    for(int fm=0;fm<4;fm++)
      ag[fm] = *reinterpret_cast<const bfx8*>(Ac + (wm*64 + 32 + fm*8 + rpb)*128 + rsw);
    STAGE_B(Pb,0,kpk); STAGE_B(Pb,1,kpk);
    __builtin_amdgcn_s_barrier();
    asm volatile("s_waitcnt lgkmcnt(0)" ::: "memory");
    __builtin_amdgcn_sched_barrier(0);
    __builtin_amdgcn_s_setprio(1);
    #pragma unroll
    for(int fm=0;fm<4;fm++)
      #pragma unroll
      for(int fn=0;fn<4;fn++)
        acc[4+fm][fn] = __builtin_amdgcn_mfma_f32_16x16x32_bf16(ag[fm], bfr[fn], acc[4+fm][fn], 0,0,0);
    __builtin_amdgcn_s_setprio(0);
    // counted drain: tile kt+1's 4 loads (issued during kt-1) land; kt+2's 4 stay in flight
    asm volatile("s_waitcnt vmcnt(4)" ::: "memory");
    __builtin_amdgcn_s_barrier();

    cur = cur+1==3 ? 0 : cur+1;
  }
  #undef STAGE_A
  #undef STAGE_B

  // epilogue: row = bm0 + wm*128 + fm*16 + lg*4 + rr ; col = bn0 + wn*64 + fn*16 + lr
  #pragma unroll
  for(int fm=0;fm<8;fm++){
    #pragma unroll
    for(int rr=0;rr<4;rr++){
      int row = bm0 + wm*128 + fm*16 + (lg<<2) + rr;
      #pragma unroll
      for(int fn=0;fn<4;fn++){
        int col = bn0 + wn*64 + fn*16 + lr;
        size_t idx = (size_t)row*N + col;
        float v = acc[fm][fn][rr];
        if(EPI==0){
          reinterpret_cast<unsigned short*>(out)[idx] = f2bf(v);
        } else if(EPI==1){
          reinterpret_cast<float*>(out)[idx] = resid[idx] + v;
        } else {
          float g = bf2f(gbuf[idx]);
          float sg = g / (1.0f + __expf(-g));
          reinterpret_cast<unsigned short*>(out)[idx] = f2bf(sg*v);
        }
      }
    }
  }
}

// ---------------- Flash attention, causal (unchanged from round 4) ----------------
__global__ __launch_bounds__(256) void k_attn(const unsigned short* __restrict__ Q,
                                              const unsigned short* __restrict__ Kb,
                                              int ldqk,
                                              const unsigned short* __restrict__ VT,
                                              unsigned short* __restrict__ O){
  __shared__ unsigned short Klds[64*128];
  __shared__ unsigned short Vlds[128*64];
  __shared__ unsigned short Plds[4][16*72];

  int bid = blockIdx.x;
  int xcd = bid & 7, idx = bid >> 3;
  int bh = xcd*4 + (idx & 3);
  int qt = 31 - (idx >> 2);
  int h = bh & 15, b = bh >> 4;
  int q0 = qt << 6;
  int t = threadIdx.x, w = t>>6, l = t&63, lr = l&15, lg = l>>4;
  int q0w = q0 + (w<<4);

  bfx8 qf[4];
  const unsigned short* qrow = Q + (size_t)(b*SEQL + q0w + lr)*ldqk + h*HD;
  #pragma unroll
  for(int ds=0;ds<4;ds++) qf[ds] = *reinterpret_cast<const bfx8*>(qrow + ds*32 + lg*8);

  f32x4 z = {0.f,0.f,0.f,0.f};
  f32x4 oacc[8];
  #pragma unroll
  for(int i=0;i<8;i++) oacc[i] = z;
  float m_run = -1e30f, l_run = 0.f;

  int srow = t>>3, sch = t&7;
  int ntile = qt + 1;
  for(int tl=0; tl<ntile; ++tl){
    int k0 = tl << 6;
    __syncthreads();
    #pragma unroll
    for(int pr=0;pr<2;pr++){
      int row = srow + (pr<<5);
      const unsigned short* ks = Kb + (size_t)(b*SEQL + k0 + row)*ldqk + h*HD;
      #pragma unroll
      for(int pc=0;pc<2;pc++){
        int cl = sch + (pc<<3);
        *reinterpret_cast<bfx8*>((char*)Klds + row*256 + ((cl ^ (row&7))<<4)) =
            *reinterpret_cast<const bfx8*>(ks + cl*8);
      }
    }
    #pragma unroll
    for(int pr=0;pr<4;pr++){
      int row = srow + (pr<<5);
      const unsigned short* vs = VT + ((size_t)((b*NH + h)*HD + row))*SEQL + k0;
      *reinterpret_cast<bfx8*>((char*)Vlds + row*128 + ((sch ^ (row&7))<<4)) =
          *reinterpret_cast<const bfx8*>(vs + sch*8);
    }
    __syncthreads();

    f32x4 sAcc[4];
    sAcc[0]=z; sAcc[1]=z; sAcc[2]=z; sAcc[3]=z;
    #pragma unroll
    for(int ds=0;ds<4;ds++){
      int cha = (ds<<2) + lg;
      #pragma unroll
      for(int kg=0;kg<4;kg++){
        int row = (kg<<4) + lr;
        bfx8 ka = *reinterpret_cast<const bfx8*>((char*)Klds + row*256 + ((cha ^ (row&7))<<4));
        sAcc[kg] = __builtin_amdgcn_mfma_f32_16x16x32_bf16(ka, qf[ds], sAcc[kg], 0,0,0);
      }
    }
    int qg = q0w + lr;
    float p[16];
    float mx = -1e30f;
    #pragma unroll
    for(int kg=0;kg<4;kg++){
      #pragma unroll
      for(int r=0;r<4;r++){
        int kk = k0 + (kg<<4) + (lg<<2) + r;
        float v = (kk <= qg) ? sAcc[kg][r] : -1e30f;
        p[kg*4+r] = v; mx = fmaxf(mx, v);
      }
    }
    mx = fmaxf(mx, __shfl_xor(mx,16));
    mx = fmaxf(mx, __shfl_xor(mx,32));
    float m_new = fmaxf(m_run, mx);
    float fac = __expf(m_run - m_new);
    float ts = 0.f;
    #pragma unroll
    for(int i=0;i<16;i++){ p[i] = __expf(p[i]-m_new); ts += p[i]; }
    ts += __shfl_xor(ts,16); ts += __shfl_xor(ts,32);
    l_run = l_run*fac + ts;
    m_run = m_new;
    char* pb = (char*)&Plds[w][0] + lr*144 + lg*8;
    #pragma unroll
    for(int kg=0;kg<4;kg++){
      unsigned pa = (unsigned)f2bf(p[kg*4+0]) | ((unsigned)f2bf(p[kg*4+1])<<16);
      unsigned pc = (unsigned)f2bf(p[kg*4+2]) | ((unsigned)f2bf(p[kg*4+3])<<16);
      *reinterpret_cast<uint2*>(pb + kg*32) = make_uint2(pa, pc);
    }
    float facr[4];
    #pragma unroll
    for(int r=0;r<4;r++) facr[r] = __shfl(fac, (lg<<2)+r);
    #pragma unroll
    for(int db=0;db<8;db++){
      f32x4 o = oacc[db];
      o[0]*=facr[0]; o[1]*=facr[1]; o[2]*=facr[2]; o[3]*=facr[3];
      oacc[db] = o;
    }
    __syncthreads();
    #pragma unroll
    for(int kh=0;kh<2;kh++){
      bfx8 pf = *reinterpret_cast<const bfx8*>((char*)&Plds[w][0] + lr*144 + kh*64 + lg*16);
      #pragma unroll
      for(int db=0;db<8;db++){
        int row = (db<<4) + lr;
        int lc = (kh<<2) + lg;
        bfx8 vf = *reinterpret_cast<const bfx8*>((char*)Vlds + row*128 + ((lc ^ (row&7))<<4));
        oacc[db] = __builtin_amdgcn_mfma_f32_16x16x32_bf16(pf, vf, oacc[db], 0,0,0);
      }
    }
  }
  float lsr[4];
  #pragma unroll
  for(int r=0;r<4;r++) lsr[r] = 1.0f / __shfl(l_run, (lg<<2)+r);
  #pragma unroll
  for(int db=0;db<8;db++){
    #pragma unroll
    for(int r=0;r<4;r++){
      int row = q0w + (lg<<2) + r;
      O[((size_t)((b*SEQL + row)*NH) + h)*HD + (db<<4) + lr] = f2bf(oacc[db][r]*lsr[r]);
    }
  }
}

// ---------------- host launcher (workspace plan unchanged from round 4) ----------------
extern "C" void kernel_launch(void* const* d_in, const int* in_sizes, int n_in,
                              void* d_out, int out_size, void* d_ws, size_t ws_size,
                              hipStream_t stream){
  const float* x   = (const float*)d_in[0];
  const float* anw = (const float*)d_in[1];
  const float* qw  = (const float*)d_in[2];
  const float* kw  = (const float*)d_in[3];
  const float* vw  = (const float*)d_in[4];
  const float* ow  = (const float*)d_in[5];
  const float* fnw = (const float*)d_in[6];
  const float* gw  = (const float*)d_in[7];
  const float* uw  = (const float*)d_in[8];
  const float* dw  = (const float*)d_in[9];
  float* out = (float*)d_out;

  char* ws = (char*)d_ws;
  size_t off = 0;
  auto alloc = [&](size_t bytes)->char*{ char* p = ws + off; off += (bytes + 255) & ~(size_t)255; return p; };
  unsigned short* Wbuf = (unsigned short*)alloc((size_t)INTERD*HID*2);     // 32 MB
  unsigned short* hb   = (unsigned short*)alloc((size_t)NTOK*HID*2);       // 16 MB
  unsigned short* qkvb = (unsigned short*)alloc((size_t)NTOK*3*HID*2);     // 48 MB
  unsigned short* aob  = (unsigned short*)alloc((size_t)NTOK*HID*2);       // 16 MB
  float*          x1   = (float*)alloc((size_t)NTOK*HID*4);                // 32 MB
  float*          cosb = (float*)alloc((size_t)SEQL*64*4);
  float*          sinb = (float*)alloc((size_t)SEQL*64*4);
  unsigned short* gb   = qkvb;                // 64 MB overlay (qkvb+aob), dead after O-proj
  unsigned short* VT   = (unsigned short*)x1; // 16 MB overlay: x1 written only after attn
  if(ws_size < off){ k_sentinel<<<1,1,0,stream>>>(out); return; }

  k_ropetab<<<SEQL, 64, 0, stream>>>(cosb, sinb);

  // ---- attention sublayer ----
  k_rmsnorm<<<NTOK, 256, 0, stream>>>(x, anw, hb);
  k_cvt<<<HID*HID/1024, 256, 0, stream>>>(qw, Wbuf,             HID*HID/4);
  k_cvt<<<HID*HID/1024, 256, 0, stream>>>(kw, Wbuf +   HID*HID, HID*HID/4);
  k_cvt<<<HID*HID/1024, 256, 0, stream>>>(vw, Wbuf + 2*HID*HID, HID*HID/4);
  k_gemm<0><<<(NTOK/256)*(3*HID/256), 512, 0, stream>>>(hb, Wbuf, qkvb, nullptr, nullptr, NTOK, 3*HID, HID); // 384 blk
  k_rope<<<(NTOK*NH*64)/256, 256, 0, stream>>>(qkvb,        3*HID, cosb, sinb, 0.08838834764831845f);
  k_rope<<<(NTOK*NH*64)/256, 256, 0, stream>>>(qkvb +  HID, 3*HID, cosb, sinb, 1.0f);
  k_transpose_v<<<NBATCH*NH*(SEQL/64), 256, 0, stream>>>(qkvb + 2*HID, 3*HID, VT);
  k_attn<<<(SEQL/64)*NBATCH*NH, 256, 0, stream>>>(qkvb, qkvb + HID, 3*HID, VT, aob);
  k_cvt<<<HID*HID/1024, 256, 0, stream>>>(ow, Wbuf, HID*HID/4);
  k_gemm<1><<<(NTOK/256)*(HID/256), 512, 0, stream>>>(aob, Wbuf, x1, x, nullptr, NTOK, HID, HID);            // 128 blk

  // ---- MLP sublayer ----
  k_rmsnorm<<<NTOK, 256, 0, stream>>>(x1, fnw, hb);
  k_cvt<<<INTERD*HID/1024, 256, 0, stream>>>(gw, Wbuf, INTERD*HID/4);
  k_gemm<0><<<(NTOK/256)*(INTERD/256), 512, 0, stream>>>(hb, Wbuf, gb, nullptr, nullptr, NTOK, INTERD, HID); // 512 blk
  k_cvt<<<INTERD*HID/1024, 256, 0, stream>>>(uw, Wbuf, INTERD*HID/4);
  k_gemm<2><<<(NTOK/256)*(INTERD/256), 512, 0, stream>>>(hb, Wbuf, gb, nullptr, gb, NTOK, INTERD, HID);
  k_cvt<<<INTERD*HID/1024, 256, 0, stream>>>(dw, Wbuf, INTERD*HID/4);
  k_gemm<1><<<(NTOK/256)*(HID/256), 512, 0, stream>>>(gb, Wbuf, out, x1, nullptr, NTOK, HID, INTERD);        // 128 blk
}

// Round 6
// 989.233 us; speedup vs baseline: 1.0018x; 1.0018x over previous
//
#include <hip/hip_runtime.h>
#include <math.h>

#define HID 2048
#define NH 16
#define HD 128
#define INTERD 8192
#define SEQL 2048
#define NBATCH 2
#define NTOK (NBATCH*SEQL)

typedef float f32x4 __attribute__((ext_vector_type(4)));
typedef __bf16 bfx8 __attribute__((ext_vector_type(8)));

__device__ __forceinline__ float bf2f(unsigned short u){
  union { float f; unsigned v; } c; c.v = ((unsigned)u)<<16; return c.f;
}
__device__ __forceinline__ unsigned short f2bf(float f){
  union { float f; unsigned v; } c; c.f = f;
  unsigned r = c.v + 0x7FFFu + ((c.v>>16)&1u);   // RNE
  return (unsigned short)(r>>16);
}

// async global->LDS, 16B/lane; LDS dest = wave-uniform base + lane*16 (proven r3/r4).
__device__ __forceinline__ void gll16(const unsigned short* g, void* l){
  __builtin_amdgcn_global_load_lds(
      (const __attribute__((address_space(1))) unsigned int*)(size_t)(const void*)g,
      (__attribute__((address_space(3))) unsigned int*)(unsigned int)(size_t)l,
      16, 0, 0);
}

__global__ void k_sentinel(float* out){ out[0] = 1.0e9f; }

// ---------------- fp32 -> bf16 conversion (weights) ----------------
__global__ __launch_bounds__(256) void k_cvt(const float* __restrict__ in,
                                             unsigned short* __restrict__ out, int n4){
  int i = blockIdx.x*256 + threadIdx.x;
  if(i >= n4) return;
  float4 v = reinterpret_cast<const float4*>(in)[i];
  ushort4 o;
  o.x = f2bf(v.x); o.y = f2bf(v.y); o.z = f2bf(v.z); o.w = f2bf(v.w);
  reinterpret_cast<ushort4*>(out)[i] = o;
}

// ---------------- RMSNorm (fp32 in) -> bf16 out ----------------
__global__ __launch_bounds__(256) void k_rmsnorm(const float* __restrict__ x,
                                                 const float* __restrict__ w,
                                                 unsigned short* __restrict__ out){
  int row = blockIdx.x, t = threadIdx.x;
  const float4* xr = reinterpret_cast<const float4*>(x + (size_t)row*HID);
  float4 a = xr[2*t], b = xr[2*t+1];
  float ss = a.x*a.x+a.y*a.y+a.z*a.z+a.w*a.w + b.x*b.x+b.y*b.y+b.z*b.z+b.w*b.w;
  #pragma unroll
  for(int o=1;o<64;o<<=1) ss += __shfl_xor(ss, o);
  __shared__ float red[4];
  if((t&63)==0) red[t>>6] = ss;
  __syncthreads();
  float sc = rsqrtf((red[0]+red[1]+red[2]+red[3])*(1.0f/HID) + 1e-6f);
  const float4* wr = reinterpret_cast<const float4*>(w);
  float4 wa = wr[2*t], wb = wr[2*t+1];
  ushort4 o1, o2;
  o1.x=f2bf(a.x*sc*wa.x); o1.y=f2bf(a.y*sc*wa.y); o1.z=f2bf(a.z*sc*wa.z); o1.w=f2bf(a.w*sc*wa.w);
  o2.x=f2bf(b.x*sc*wb.x); o2.y=f2bf(b.y*sc*wb.y); o2.z=f2bf(b.z*sc*wb.z); o2.w=f2bf(b.w*sc*wb.w);
  ushort4* orow = reinterpret_cast<ushort4*>(out + (size_t)row*HID);
  orow[2*t] = o1; orow[2*t+1] = o2;
}

// ---------------- RoPE tables ----------------
__global__ void k_ropetab(float* __restrict__ cs, float* __restrict__ sn){
  int s = blockIdx.x, j = threadIdx.x;   // 64 threads
  float invf = powf(10000.0f, -(float)j*(1.0f/64.0f));
  float ang = (float)s * invf;
  float c, si;
  sincosf(ang, &si, &c);
  cs[s*64+j] = c; sn[s*64+j] = si;
}

// ---------------- RoPE apply in-place on bf16 [tok][ld] at head offset ----------------
__global__ __launch_bounds__(256) void k_rope(unsigned short* qk, int ld,
                                              const float* __restrict__ cs,
                                              const float* __restrict__ sn, float scale){
  int gid = blockIdx.x*256 + threadIdx.x;
  int j = gid & 63;
  int rh = gid >> 6;               // tok*NH + h
  int tok = rh >> 4, h = rh & 15;
  int s = tok & (SEQL-1);
  unsigned short* base = qk + (size_t)tok*ld + h*HD;
  float c = cs[s*64+j], sv = sn[s*64+j];
  float x1 = bf2f(base[j]), x2 = bf2f(base[j+64]);
  base[j]    = f2bf((x1*c - x2*sv)*scale);
  base[j+64] = f2bf((x2*c + x1*sv)*scale);
}

// ---------------- V transpose: VT[b,h,d,s] <- V[tok][ld] (bf16) ----------------
__global__ __launch_bounds__(256) void k_transpose_v(const unsigned short* __restrict__ V,
                                                     int ld,
                                                     unsigned short* __restrict__ VT){
  __shared__ unsigned short T[64*136];
  int bid = blockIdx.x;
  int sb = bid & 31, h = (bid>>5) & 15, b = bid>>9;
  int t = threadIdx.x;
  int s0 = sb<<6;
  int sl = t>>2, dc = (t&3)<<5;
  const unsigned short* src = V + (size_t)(b*SEQL + s0 + sl)*ld + h*HD + dc;
  #pragma unroll
  for(int p=0;p<4;p++){
    bfx8 v = *reinterpret_cast<const bfx8*>(src + p*8);
    *reinterpret_cast<bfx8*>(&T[sl*136 + dc + p*8]) = v;
  }
  __syncthreads();
  int d = t>>1, sh = (t&1)<<5;
  unsigned short* dst = VT + ((size_t)((b*NH + h)*HD + d))*SEQL + s0 + sh;
  #pragma unroll
  for(int p=0;p<4;p++){
    union { bfx8 v; unsigned short u[8]; } o;
    #pragma unroll
    for(int j=0;j<8;j++) o.u[j] = T[(sh + p*8 + j)*136 + d];
    *reinterpret_cast<bfx8*>(dst + p*8) = o.v;
  }
}

// ==================== GEMM: C[M,N] = A[M,K] * W[N,K]^T  (bf16 in, fp32 acc) ===========
// r3 scaffold (proven: 0 conflicts, correct) with m97 wave-tile: 256 thr = 4 waves,
// tile 128x128, BK=64; wave-tile 64x64 (4x4 16x16 frags) -> 16 ds_read_b128 : 32 MFMA
// per wave per K-tile (vs r3's 20:32). Single-buffer, 2 barriers/K-step, gll16 staging
// with pre-swizzled source (chunk ^ (row&7) involution).
// EPI 0: bf16.  EPI 1: fp32 = resid + acc.  EPI 2: bf16 = silu(gbuf)*acc.
template<int EPI>
__global__ __launch_bounds__(256) void k_gemm(const unsigned short* __restrict__ A,
                                              const unsigned short* __restrict__ W,
                                              void* out, const float* __restrict__ resid,
                                              const unsigned short* gbuf,
                                              int M, int N, int K){
  __shared__ unsigned short Alds[128*64];
  __shared__ unsigned short Wlds[128*64];
  int nwg = gridDim.x;
  int bid = blockIdx.x;
  bid = (bid & 7)*(nwg>>3) + (bid>>3);     // XCD-aware swizzle (all grids %8==0)
  int nbn = N >> 7;
  int bm0 = (bid / nbn) << 7, bn0 = (bid % nbn) << 7;
  int t = threadIdx.x, w = t>>6, l = t&63, lr = l&15, lg = l>>4;
  int wm = w>>1, wn = w&1;
  int lrow = l>>3, lcs = (l&7) ^ lrow;     // pre-swizzled source chunk (involution)

  f32x4 z = {0.f,0.f,0.f,0.f};
  f32x4 acc[4][4];
  #pragma unroll
  for(int i=0;i<4;i++){ acc[i][0]=z; acc[i][1]=z; acc[i][2]=z; acc[i][3]=z; }

  for(int k0=0;k0<K;k0+=64){
    __syncthreads();                        // protect previous tile's reads
    #pragma unroll
    for(int p=0;p<4;p++){
      int br = (w<<5) + (p<<3);             // 8 rows per wave per pass
      gll16(A + (size_t)(bm0+br+lrow)*K + k0 + lcs*8, (char*)Alds + br*128);
      gll16(W + (size_t)(bn0+br+lrow)*K + k0 + lcs*8, (char*)Wlds + br*128);
    }
    __syncthreads();
    #pragma unroll
    for(int ks=0;ks<2;ks++){
      bfx8 af[4], bfr[4];
      #pragma unroll
      for(int fm=0;fm<4;fm++){
        int row = wm*64 + fm*16 + lr;
        af[fm] = *reinterpret_cast<const bfx8*>((const char*)Alds
                   + row*128 + ((((ks<<2)+lg) ^ (row&7))<<4));
      }
      #pragma unroll
      for(int fn=0;fn<4;fn++){
        int row = wn*64 + fn*16 + lr;
        bfr[fn] = *reinterpret_cast<const bfx8*>((const char*)Wlds
                   + row*128 + ((((ks<<2)+lg) ^ (row&7))<<4));
      }
      #pragma unroll
      for(int fm=0;fm<4;fm++)
        #pragma unroll
        for(int fn=0;fn<4;fn++)
          acc[fm][fn] = __builtin_amdgcn_mfma_f32_16x16x32_bf16(af[fm], bfr[fn], acc[fm][fn], 0,0,0);
    }
  }

  // epilogue: C row = bm0 + wm*64 + fm*16 + lg*4 + rr ; col = bn0 + wn*64 + fn*16 + lr
  #pragma unroll
  for(int fm=0;fm<4;fm++){
    #pragma unroll
    for(int rr=0;rr<4;rr++){
      int row = bm0 + wm*64 + fm*16 + (lg<<2) + rr;
      #pragma unroll
      for(int fn=0;fn<4;fn++){
        int col = bn0 + wn*64 + fn*16 + lr;
        size_t idx = (size_t)row*N + col;
        float v = acc[fm][fn][rr];
        if(EPI==0){
          reinterpret_cast<unsigned short*>(out)[idx] = f2bf(v);
        } else if(EPI==1){
          reinterpret_cast<float*>(out)[idx] = resid[idx] + v;
        } else {
          float g = bf2f(gbuf[idx]);
          float sg = g / (1.0f + __expf(-g));
          reinterpret_cast<unsigned short*>(out)[idx] = f2bf(sg*v);
        }
      }
    }
  }
}

// ---------------- Flash attention, causal (unchanged from rounds 4/5) ----------------
__global__ __launch_bounds__(256) void k_attn(const unsigned short* __restrict__ Q,
                                              const unsigned short* __restrict__ Kb,
                                              int ldqk,
                                              const unsigned short* __restrict__ VT,
                                              unsigned short* __restrict__ O){
  __shared__ unsigned short Klds[64*128];
  __shared__ unsigned short Vlds[128*64];
  __shared__ unsigned short Plds[4][16*72];

  int bid = blockIdx.x;
  int xcd = bid & 7, idx = bid >> 3;
  int bh = xcd*4 + (idx & 3);
  int qt = 31 - (idx >> 2);
  int h = bh & 15, b = bh >> 4;
  int q0 = qt << 6;
  int t = threadIdx.x, w = t>>6, l = t&63, lr = l&15, lg = l>>4;
  int q0w = q0 + (w<<4);

  bfx8 qf[4];
  const unsigned short* qrow = Q + (size_t)(b*SEQL + q0w + lr)*ldqk + h*HD;
  #pragma unroll
  for(int ds=0;ds<4;ds++) qf[ds] = *reinterpret_cast<const bfx8*>(qrow + ds*32 + lg*8);

  f32x4 z = {0.f,0.f,0.f,0.f};
  f32x4 oacc[8];
  #pragma unroll
  for(int i=0;i<8;i++) oacc[i] = z;
  float m_run = -1e30f, l_run = 0.f;

  int srow = t>>3, sch = t&7;
  int ntile = qt + 1;
  for(int tl=0; tl<ntile; ++tl){
    int k0 = tl << 6;
    __syncthreads();
    #pragma unroll
    for(int pr=0;pr<2;pr++){
      int row = srow + (pr<<5);
      const unsigned short* ks = Kb + (size_t)(b*SEQL + k0 + row)*ldqk + h*HD;
      #pragma unroll
      for(int pc=0;pc<2;pc++){
        int cl = sch + (pc<<3);
        *reinterpret_cast<bfx8*>((char*)Klds + row*256 + ((cl ^ (row&7))<<4)) =
            *reinterpret_cast<const bfx8*>(ks + cl*8);
      }
    }
    #pragma unroll
    for(int pr=0;pr<4;pr++){
      int row = srow + (pr<<5);
      const unsigned short* vs = VT + ((size_t)((b*NH + h)*HD + row))*SEQL + k0;
      *reinterpret_cast<bfx8*>((char*)Vlds + row*128 + ((sch ^ (row&7))<<4)) =
          *reinterpret_cast<const bfx8*>(vs + sch*8);
    }
    __syncthreads();

    f32x4 sAcc[4];
    sAcc[0]=z; sAcc[1]=z; sAcc[2]=z; sAcc[3]=z;
    #pragma unroll
    for(int ds=0;ds<4;ds++){
      int cha = (ds<<2) + lg;
      #pragma unroll
      for(int kg=0;kg<4;kg++){
        int row = (kg<<4) + lr;
        bfx8 ka = *reinterpret_cast<const bfx8*>((char*)Klds + row*256 + ((cha ^ (row&7))<<4));
        sAcc[kg] = __builtin_amdgcn_mfma_f32_16x16x32_bf16(ka, qf[ds], sAcc[kg], 0,0,0);
      }
    }
    int qg = q0w + lr;
    float p[16];
    float mx = -1e30f;
    #pragma unroll
    for(int kg=0;kg<4;kg++){
      #pragma unroll
      for(int r=0;r<4;r++){
        int kk = k0 + (kg<<4) + (lg<<2) + r;
        float v = (kk <= qg) ? sAcc[kg][r] : -1e30f;
        p[kg*4+r] = v; mx = fmaxf(mx, v);
      }
    }
    mx = fmaxf(mx, __shfl_xor(mx,16));
    mx = fmaxf(mx, __shfl_xor(mx,32));
    float m_new = fmaxf(m_run, mx);
    float fac = __expf(m_run - m_new);
    float ts = 0.f;
    #pragma unroll
    for(int i=0;i<16;i++){ p[i] = __expf(p[i]-m_new); ts += p[i]; }
    ts += __shfl_xor(ts,16); ts += __shfl_xor(ts,32);
    l_run = l_run*fac + ts;
    m_run = m_new;
    char* pb = (char*)&Plds[w][0] + lr*144 + lg*8;
    #pragma unroll
    for(int kg=0;kg<4;kg++){
      unsigned pa = (unsigned)f2bf(p[kg*4+0]) | ((unsigned)f2bf(p[kg*4+1])<<16);
      unsigned pc = (unsigned)f2bf(p[kg*4+2]) | ((unsigned)f2bf(p[kg*4+3])<<16);
      *reinterpret_cast<uint2*>(pb + kg*32) = make_uint2(pa, pc);
    }
    float facr[4];
    #pragma unroll
    for(int r=0;r<4;r++) facr[r] = __shfl(fac, (lg<<2)+r);
    #pragma unroll
    for(int db=0;db<8;db++){
      f32x4 o = oacc[db];
      o[0]*=facr[0]; o[1]*=facr[1]; o[2]*=facr[2]; o[3]*=facr[3];
      oacc[db] = o;
    }
    __syncthreads();
    #pragma unroll
    for(int kh=0;kh<2;kh++){
      bfx8 pf = *reinterpret_cast<const bfx8*>((char*)&Plds[w][0] + lr*144 + kh*64 + lg*16);
      #pragma unroll
      for(int db=0;db<8;db++){
        int row = (db<<4) + lr;
        int lc = (kh<<2) + lg;
        bfx8 vf = *reinterpret_cast<const bfx8*>((char*)Vlds + row*128 + ((lc ^ (row&7))<<4));
        oacc[db] = __builtin_amdgcn_mfma_f32_16x16x32_bf16(pf, vf, oacc[db], 0,0,0);
      }
    }
  }
  float lsr[4];
  #pragma unroll
  for(int r=0;r<4;r++) lsr[r] = 1.0f / __shfl(l_run, (lg<<2)+r);
  #pragma unroll
  for(int db=0;db<8;db++){
    #pragma unroll
    for(int r=0;r<4;r++){
      int row = q0w + (lg<<2) + r;
      O[((size_t)((b*SEQL + row)*NH) + h)*HD + (db<<4) + lr] = f2bf(oacc[db][r]*lsr[r]);
    }
  }
}

// ---------------- host launcher (workspace plan unchanged from rounds 4/5) ------------
extern "C" void kernel_launch(void* const* d_in, const int* in_sizes, int n_in,
                              void* d_out, int out_size, void* d_ws, size_t ws_size,
                              hipStream_t stream){
  const float* x   = (const float*)d_in[0];
  const float* anw = (const float*)d_in[1];
  const float* qw  = (const float*)d_in[2];
  const float* kw  = (const float*)d_in[3];
  const float* vw  = (const float*)d_in[4];
  const float* ow  = (const float*)d_in[5];
  const float* fnw = (const float*)d_in[6];
  const float* gw  = (const float*)d_in[7];
  const float* uw  = (const float*)d_in[8];
  const float* dw  = (const float*)d_in[9];
  float* out = (float*)d_out;

  char* ws = (char*)d_ws;
  size_t off = 0;
  auto alloc = [&](size_t bytes)->char*{ char* p = ws + off; off += (bytes + 255) & ~(size_t)255; return p; };
  unsigned short* Wbuf = (unsigned short*)alloc((size_t)INTERD*HID*2);     // 32 MB
  unsigned short* hb   = (unsigned short*)alloc((size_t)NTOK*HID*2);       // 16 MB
  unsigned short* qkvb = (unsigned short*)alloc((size_t)NTOK*3*HID*2);     // 48 MB
  unsigned short* aob  = (unsigned short*)alloc((size_t)NTOK*HID*2);       // 16 MB
  float*          x1   = (float*)alloc((size_t)NTOK*HID*4);                // 32 MB
  float*          cosb = (float*)alloc((size_t)SEQL*64*4);
  float*          sinb = (float*)alloc((size_t)SEQL*64*4);
  unsigned short* gb   = qkvb;                // 64 MB overlay (qkvb+aob), dead after O-proj
  unsigned short* VT   = (unsigned short*)x1; // 16 MB overlay: x1 written only after attn
  if(ws_size < off){ k_sentinel<<<1,1,0,stream>>>(out); return; }

  k_ropetab<<<SEQL, 64, 0, stream>>>(cosb, sinb);

  // ---- attention sublayer ----
  k_rmsnorm<<<NTOK, 256, 0, stream>>>(x, anw, hb);
  k_cvt<<<HID*HID/1024, 256, 0, stream>>>(qw, Wbuf,             HID*HID/4);
  k_cvt<<<HID*HID/1024, 256, 0, stream>>>(kw, Wbuf +   HID*HID, HID*HID/4);
  k_cvt<<<HID*HID/1024, 256, 0, stream>>>(vw, Wbuf + 2*HID*HID, HID*HID/4);
  k_gemm<0><<<(NTOK/128)*(3*HID/128), 256, 0, stream>>>(hb, Wbuf, qkvb, nullptr, nullptr, NTOK, 3*HID, HID); // 1536 blk
  k_rope<<<(NTOK*NH*64)/256, 256, 0, stream>>>(qkvb,        3*HID, cosb, sinb, 0.08838834764831845f);
  k_rope<<<(NTOK*NH*64)/256, 256, 0, stream>>>(qkvb +  HID, 3*HID, cosb, sinb, 1.0f);
  k_transpose_v<<<NBATCH*NH*(SEQL/64), 256, 0, stream>>>(qkvb + 2*HID, 3*HID, VT);
  k_attn<<<(SEQL/64)*NBATCH*NH, 256, 0, stream>>>(qkvb, qkvb + HID, 3*HID, VT, aob);
  k_cvt<<<HID*HID/1024, 256, 0, stream>>>(ow, Wbuf, HID*HID/4);
  k_gemm<1><<<(NTOK/128)*(HID/128), 256, 0, stream>>>(aob, Wbuf, x1, x, nullptr, NTOK, HID, HID);            // 512 blk

  // ---- MLP sublayer ----
  k_rmsnorm<<<NTOK, 256, 0, stream>>>(x1, fnw, hb);
  k_cvt<<<INTERD*HID/1024, 256, 0, stream>>>(gw, Wbuf, INTERD*HID/4);
  k_gemm<0><<<(NTOK/128)*(INTERD/128), 256, 0, stream>>>(hb, Wbuf, gb, nullptr, nullptr, NTOK, INTERD, HID); // 2048 blk
  k_cvt<<<INTERD*HID/1024, 256, 0, stream>>>(uw, Wbuf, INTERD*HID/4);
  k_gemm<2><<<(NTOK/128)*(INTERD/128), 256, 0, stream>>>(hb, Wbuf, gb, nullptr, gb, NTOK, INTERD, HID);
  k_cvt<<<INTERD*HID/1024, 256, 0, stream>>>(dw, Wbuf, INTERD*HID/4);
  k_gemm<1><<<(NTOK/128)*(HID/128), 256, 0, stream>>>(gb, Wbuf, out, x1, nullptr, NTOK, HID, INTERD);        // 512 blk
}

// Round 7
// 918.523 us; speedup vs baseline: 1.0789x; 1.0770x over previous
//
#include <hip/hip_runtime.h>
#include <math.h>

#define HID 2048
#define NH 16
#define HD 128
#define INTERD 8192
#define SEQL 2048
#define NBATCH 2
#define NTOK (NBATCH*SEQL)

typedef float f32x4 __attribute__((ext_vector_type(4)));
typedef __bf16 bfx8 __attribute__((ext_vector_type(8)));

__device__ __forceinline__ float bf2f(unsigned short u){
  union { float f; unsigned v; } c; c.v = ((unsigned)u)<<16; return c.f;
}
__device__ __forceinline__ unsigned short f2bf(float f){
  union { float f; unsigned v; } c; c.f = f;
  unsigned r = c.v + 0x7FFFu + ((c.v>>16)&1u);   // RNE
  return (unsigned short)(r>>16);
}

// async global->LDS, 16B/lane; LDS dest = wave-uniform base + lane*16 (proven r3-r6).
__device__ __forceinline__ void gll16(const unsigned short* g, void* l){
  __builtin_amdgcn_global_load_lds(
      (const __attribute__((address_space(1))) unsigned int*)(size_t)(const void*)g,
      (__attribute__((address_space(3))) unsigned int*)(unsigned int)(size_t)l,
      16, 0, 0);
}

__global__ void k_sentinel(float* out){ out[0] = 1.0e9f; }

// ---------------- fp32 -> bf16 conversion (weights) ----------------
__global__ __launch_bounds__(256) void k_cvt(const float* __restrict__ in,
                                             unsigned short* __restrict__ out, int n4){
  int i = blockIdx.x*256 + threadIdx.x;
  if(i >= n4) return;
  float4 v = reinterpret_cast<const float4*>(in)[i];
  ushort4 o;
  o.x = f2bf(v.x); o.y = f2bf(v.y); o.z = f2bf(v.z); o.w = f2bf(v.w);
  reinterpret_cast<ushort4*>(out)[i] = o;
}

// ---------------- RMSNorm (fp32 in) -> bf16 out ----------------
__global__ __launch_bounds__(256) void k_rmsnorm(const float* __restrict__ x,
                                                 const float* __restrict__ w,
                                                 unsigned short* __restrict__ out){
  int row = blockIdx.x, t = threadIdx.x;
  const float4* xr = reinterpret_cast<const float4*>(x + (size_t)row*HID);
  float4 a = xr[2*t], b = xr[2*t+1];
  float ss = a.x*a.x+a.y*a.y+a.z*a.z+a.w*a.w + b.x*b.x+b.y*b.y+b.z*b.z+b.w*b.w;
  #pragma unroll
  for(int o=1;o<64;o<<=1) ss += __shfl_xor(ss, o);
  __shared__ float red[4];
  if((t&63)==0) red[t>>6] = ss;
  __syncthreads();
  float sc = rsqrtf((red[0]+red[1]+red[2]+red[3])*(1.0f/HID) + 1e-6f);
  const float4* wr = reinterpret_cast<const float4*>(w);
  float4 wa = wr[2*t], wb = wr[2*t+1];
  ushort4 o1, o2;
  o1.x=f2bf(a.x*sc*wa.x); o1.y=f2bf(a.y*sc*wa.y); o1.z=f2bf(a.z*sc*wa.z); o1.w=f2bf(a.w*sc*wa.w);
  o2.x=f2bf(b.x*sc*wb.x); o2.y=f2bf(b.y*sc*wb.y); o2.z=f2bf(b.z*sc*wb.z); o2.w=f2bf(b.w*sc*wb.w);
  ushort4* orow = reinterpret_cast<ushort4*>(out + (size_t)row*HID);
  orow[2*t] = o1; orow[2*t+1] = o2;
}

// ---------------- RoPE tables ----------------
__global__ void k_ropetab(float* __restrict__ cs, float* __restrict__ sn){
  int s = blockIdx.x, j = threadIdx.x;   // 64 threads
  float invf = powf(10000.0f, -(float)j*(1.0f/64.0f));
  float ang = (float)s * invf;
  float c, si;
  sincosf(ang, &si, &c);
  cs[s*64+j] = c; sn[s*64+j] = si;
}

// ---------------- RoPE apply in-place on bf16 [tok][ld] at head offset ----------------
__global__ __launch_bounds__(256) void k_rope(unsigned short* qk, int ld,
                                              const float* __restrict__ cs,
                                              const float* __restrict__ sn, float scale){
  int gid = blockIdx.x*256 + threadIdx.x;
  int j = gid & 63;
  int rh = gid >> 6;               // tok*NH + h
  int tok = rh >> 4, h = rh & 15;
  int s = tok & (SEQL-1);
  unsigned short* base = qk + (size_t)tok*ld + h*HD;
  float c = cs[s*64+j], sv = sn[s*64+j];
  float x1 = bf2f(base[j]), x2 = bf2f(base[j+64]);
  base[j]    = f2bf((x1*c - x2*sv)*scale);
  base[j+64] = f2bf((x2*c + x1*sv)*scale);
}

// ---------------- V transpose: VT[b,h,d,s] <- V[tok][ld] (bf16) ----------------
__global__ __launch_bounds__(256) void k_transpose_v(const unsigned short* __restrict__ V,
                                                     int ld,
                                                     unsigned short* __restrict__ VT){
  __shared__ unsigned short T[64*136];
  int bid = blockIdx.x;
  int sb = bid & 31, h = (bid>>5) & 15, b = bid>>9;
  int t = threadIdx.x;
  int s0 = sb<<6;
  int sl = t>>2, dc = (t&3)<<5;
  const unsigned short* src = V + (size_t)(b*SEQL + s0 + sl)*ld + h*HD + dc;
  #pragma unroll
  for(int p=0;p<4;p++){
    bfx8 v = *reinterpret_cast<const bfx8*>(src + p*8);
    *reinterpret_cast<bfx8*>(&T[sl*136 + dc + p*8]) = v;
  }
  __syncthreads();
  int d = t>>1, sh = (t&1)<<5;
  unsigned short* dst = VT + ((size_t)((b*NH + h)*HD + d))*SEQL + s0 + sh;
  #pragma unroll
  for(int p=0;p<4;p++){
    union { bfx8 v; unsigned short u[8]; } o;
    #pragma unroll
    for(int j=0;j<8;j++) o.u[j] = T[(sh + p*8 + j)*136 + d];
    *reinterpret_cast<bfx8*>(dst + p*8) = o.v;
  }
}

// ==================== GEMM: C[M,N] = A[M,K] * W[N,K]^T  (bf16 in, fp32 acc) ===========
// r6 scaffold + T3-minimum double-buffer: 256 thr = 4 waves, tile 128x128, BK=64,
// wave-tile 64x64 (4x4 frags). Per K-tile: {stage t+1 (8 gll, issued FIRST) || 16
// ds_read_b128 of tile t -> lgkmcnt(0)+sched_barrier -> 32 MFMA -> __syncthreads()
// (vmcnt(0) drain covered by the MFMA time)}. ONE barrier per K-tile.
// Work mapping: XCD-contiguous chunks, n-major within chunk (B-panel L2-resident).
// LDS swizzle: 16B-chunk ^ (row&7) via pre-swizzled gll source (0-conflict, r3-r6).
// EPI 0: bf16.  EPI 1: fp32 = resid + acc.  EPI 2: bf16 = silu(gbuf)*acc.
template<int EPI>
__global__ __launch_bounds__(256) void k_gemm(const unsigned short* __restrict__ A,
                                              const unsigned short* __restrict__ W,
                                              void* out, const float* __restrict__ resid,
                                              const unsigned short* gbuf,
                                              int M, int N, int K){
  __shared__ unsigned short Alds[2][128*64];
  __shared__ unsigned short Wlds[2][128*64];
  int nwg = gridDim.x;
  int bid = blockIdx.x;
  bid = (bid & 7)*(nwg>>3) + (bid>>3);     // XCD-aware: each XCD owns a contiguous chunk
  int nbm = M >> 7;
  int bm0 = (bid % nbm) << 7, bn0 = (bid / nbm) << 7;   // n-major within chunk
  int t = threadIdx.x, w = t>>6, l = t&63, lr = l&15, lg = l>>4;
  int wm = w>>1, wn = w&1;
  int lrow = l>>3, lcs = (l&7) ^ lrow;     // pre-swizzled source chunk (involution)
  int nt = K >> 6;

  f32x4 z = {0.f,0.f,0.f,0.f};
  f32x4 acc[4][4];
  #pragma unroll
  for(int i=0;i<4;i++){ acc[i][0]=z; acc[i][1]=z; acc[i][2]=z; acc[i][3]=z; }

  // stage one K-tile (128x64 A + 128x64 W) into buffer bb: 8 gll16 per thread
  #define STAGE(bb, kk) \
    _Pragma("unroll") \
    for(int p=0;p<4;p++){ \
      int br = (w<<5) + (p<<3); \
      gll16(A + (size_t)(bm0+br+lrow)*K + (kk) + lcs*8, (char*)Alds[bb] + br*128); \
      gll16(W + (size_t)(bn0+br+lrow)*K + (kk) + lcs*8, (char*)Wlds[bb] + br*128); \
    }

  // prologue: stage tile 0, drain, barrier
  STAGE(0, 0)
  __syncthreads();                         // emits vmcnt(0) lgkmcnt(0) + s_barrier

  for(int kt=0; kt<nt; ++kt){
    int cur = kt & 1;
    int kn = (kt+1 < nt) ? ((kt+1)<<6) : 0;   // wrap: stale-but-safe staging on last iter
    // issue next-tile staging FIRST (HBM latency starts now, hidden under MFMA below)
    STAGE(cur^1, kn)
    // 16 ds_read_b128 of current tile
    bfx8 af[2][4], bfr[2][4];
    #pragma unroll
    for(int ks=0;ks<2;ks++){
      #pragma unroll
      for(int fm=0;fm<4;fm++){
        int row = wm*64 + fm*16 + lr;
        af[ks][fm] = *reinterpret_cast<const bfx8*>((const char*)Alds[cur]
                     + row*128 + ((((ks<<2)+lg) ^ (row&7))<<4));
      }
      #pragma unroll
      for(int fn=0;fn<4;fn++){
        int row = wn*64 + fn*16 + lr;
        bfr[ks][fn] = *reinterpret_cast<const bfx8*>((const char*)Wlds[cur]
                     + row*128 + ((((ks<<2)+lg) ^ (row&7))<<4));
      }
    }
    asm volatile("s_waitcnt lgkmcnt(0)" ::: "memory");
    __builtin_amdgcn_sched_barrier(0);     // rule #18: keep MFMA below the wait
    #pragma unroll
    for(int ks=0;ks<2;ks++)
      #pragma unroll
      for(int fm=0;fm<4;fm++)
        #pragma unroll
        for(int fn=0;fn<4;fn++)
          acc[fm][fn] = __builtin_amdgcn_mfma_f32_16x16x32_bf16(af[ks][fm], bfr[ks][fn], acc[fm][fn], 0,0,0);
    // one barrier per K-tile; its vmcnt(0) (staging drain) is covered by the MFMA above
    __syncthreads();
  }
  #undef STAGE

  // epilogue: C row = bm0 + wm*64 + fm*16 + lg*4 + rr ; col = bn0 + wn*64 + fn*16 + lr
  #pragma unroll
  for(int fm=0;fm<4;fm++){
    #pragma unroll
    for(int rr=0;rr<4;rr++){
      int row = bm0 + wm*64 + fm*16 + (lg<<2) + rr;
      #pragma unroll
      for(int fn=0;fn<4;fn++){
        int col = bn0 + wn*64 + fn*16 + lr;
        size_t idx = (size_t)row*N + col;
        float v = acc[fm][fn][rr];
        if(EPI==0){
          reinterpret_cast<unsigned short*>(out)[idx] = f2bf(v);
        } else if(EPI==1){
          reinterpret_cast<float*>(out)[idx] = resid[idx] + v;
        } else {
          float g = bf2f(gbuf[idx]);
          float sg = g / (1.0f + __expf(-g));
          reinterpret_cast<unsigned short*>(out)[idx] = f2bf(sg*v);
        }
      }
    }
  }
}

// ---------------- Flash attention, causal (unchanged from rounds 4-6) ----------------
__global__ __launch_bounds__(256) void k_attn(const unsigned short* __restrict__ Q,
                                              const unsigned short* __restrict__ Kb,
                                              int ldqk,
                                              const unsigned short* __restrict__ VT,
                                              unsigned short* __restrict__ O){
  __shared__ unsigned short Klds[64*128];
  __shared__ unsigned short Vlds[128*64];
  __shared__ unsigned short Plds[4][16*72];

  int bid = blockIdx.x;
  int xcd = bid & 7, idx = bid >> 3;
  int bh = xcd*4 + (idx & 3);
  int qt = 31 - (idx >> 2);
  int h = bh & 15, b = bh >> 4;
  int q0 = qt << 6;
  int t = threadIdx.x, w = t>>6, l = t&63, lr = l&15, lg = l>>4;
  int q0w = q0 + (w<<4);

  bfx8 qf[4];
  const unsigned short* qrow = Q + (size_t)(b*SEQL + q0w + lr)*ldqk + h*HD;
  #pragma unroll
  for(int ds=0;ds<4;ds++) qf[ds] = *reinterpret_cast<const bfx8*>(qrow + ds*32 + lg*8);

  f32x4 z = {0.f,0.f,0.f,0.f};
  f32x4 oacc[8];
  #pragma unroll
  for(int i=0;i<8;i++) oacc[i] = z;
  float m_run = -1e30f, l_run = 0.f;

  int srow = t>>3, sch = t&7;
  int ntile = qt + 1;
  for(int tl=0; tl<ntile; ++tl){
    int k0 = tl << 6;
    __syncthreads();
    #pragma unroll
    for(int pr=0;pr<2;pr++){
      int row = srow + (pr<<5);
      const unsigned short* ks = Kb + (size_t)(b*SEQL + k0 + row)*ldqk + h*HD;
      #pragma unroll
      for(int pc=0;pc<2;pc++){
        int cl = sch + (pc<<3);
        *reinterpret_cast<bfx8*>((char*)Klds + row*256 + ((cl ^ (row&7))<<4)) =
            *reinterpret_cast<const bfx8*>(ks + cl*8);
      }
    }
    #pragma unroll
    for(int pr=0;pr<4;pr++){
      int row = srow + (pr<<5);
      const unsigned short* vs = VT + ((size_t)((b*NH + h)*HD + row))*SEQL + k0;
      *reinterpret_cast<bfx8*>((char*)Vlds + row*128 + ((sch ^ (row&7))<<4)) =
          *reinterpret_cast<const bfx8*>(vs + sch*8);
    }
    __syncthreads();

    f32x4 sAcc[4];
    sAcc[0]=z; sAcc[1]=z; sAcc[2]=z; sAcc[3]=z;
    #pragma unroll
    for(int ds=0;ds<4;ds++){
      int cha = (ds<<2) + lg;
      #pragma unroll
      for(int kg=0;kg<4;kg++){
        int row = (kg<<4) + lr;
        bfx8 ka = *reinterpret_cast<const bfx8*>((char*)Klds + row*256 + ((cha ^ (row&7))<<4));
        sAcc[kg] = __builtin_amdgcn_mfma_f32_16x16x32_bf16(ka, qf[ds], sAcc[kg], 0,0,0);
      }
    }
    int qg = q0w + lr;
    float p[16];
    float mx = -1e30f;
    #pragma unroll
    for(int kg=0;kg<4;kg++){
      #pragma unroll
      for(int r=0;r<4;r++){
        int kk = k0 + (kg<<4) + (lg<<2) + r;
        float v = (kk <= qg) ? sAcc[kg][r] : -1e30f;
        p[kg*4+r] = v; mx = fmaxf(mx, v);
      }
    }
    mx = fmaxf(mx, __shfl_xor(mx,16));
    mx = fmaxf(mx, __shfl_xor(mx,32));
    float m_new = fmaxf(m_run, mx);
    float fac = __expf(m_run - m_new);
    float ts = 0.f;
    #pragma unroll
    for(int i=0;i<16;i++){ p[i] = __expf(p[i]-m_new); ts += p[i]; }
    ts += __shfl_xor(ts,16); ts += __shfl_xor(ts,32);
    l_run = l_run*fac + ts;
    m_run = m_new;
    char* pb = (char*)&Plds[w][0] + lr*144 + lg*8;
    #pragma unroll
    for(int kg=0;kg<4;kg++){
      unsigned pa = (unsigned)f2bf(p[kg*4+0]) | ((unsigned)f2bf(p[kg*4+1])<<16);
      unsigned pc = (unsigned)f2bf(p[kg*4+2]) | ((unsigned)f2bf(p[kg*4+3])<<16);
      *reinterpret_cast<uint2*>(pb + kg*32) = make_uint2(pa, pc);
    }
    float facr[4];
    #pragma unroll
    for(int r=0;r<4;r++) facr[r] = __shfl(fac, (lg<<2)+r);
    #pragma unroll
    for(int db=0;db<8;db++){
      f32x4 o = oacc[db];
      o[0]*=facr[0]; o[1]*=facr[1]; o[2]*=facr[2]; o[3]*=facr[3];
      oacc[db] = o;
    }
    __syncthreads();
    #pragma unroll
    for(int kh=0;kh<2;kh++){
      bfx8 pf = *reinterpret_cast<const bfx8*>((char*)&Plds[w][0] + lr*144 + kh*64 + lg*16);
      #pragma unroll
      for(int db=0;db<8;db++){
        int row = (db<<4) + lr;
        int lc = (kh<<2) + lg;
        bfx8 vf = *reinterpret_cast<const bfx8*>((char*)Vlds + row*128 + ((lc ^ (row&7))<<4));
        oacc[db] = __builtin_amdgcn_mfma_f32_16x16x32_bf16(pf, vf, oacc[db], 0,0,0);
      }
    }
  }
  float lsr[4];
  #pragma unroll
  for(int r=0;r<4;r++) lsr[r] = 1.0f / __shfl(l_run, (lg<<2)+r);
  #pragma unroll
  for(int db=0;db<8;db++){
    #pragma unroll
    for(int r=0;r<4;r++){
      int row = q0w + (lg<<2) + r;
      O[((size_t)((b*SEQL + row)*NH) + h)*HD + (db<<4) + lr] = f2bf(oacc[db][r]*lsr[r]);
    }
  }
}

// ---------------- host launcher (workspace plan unchanged from rounds 4-6) ------------
extern "C" void kernel_launch(void* const* d_in, const int* in_sizes, int n_in,
                              void* d_out, int out_size, void* d_ws, size_t ws_size,
                              hipStream_t stream){
  const float* x   = (const float*)d_in[0];
  const float* anw = (const float*)d_in[1];
  const float* qw  = (const float*)d_in[2];
  const float* kw  = (const float*)d_in[3];
  const float* vw  = (const float*)d_in[4];
  const float* ow  = (const float*)d_in[5];
  const float* fnw = (const float*)d_in[6];
  const float* gw  = (const float*)d_in[7];
  const float* uw  = (const float*)d_in[8];
  const float* dw  = (const float*)d_in[9];
  float* out = (float*)d_out;

  char* ws = (char*)d_ws;
  size_t off = 0;
  auto alloc = [&](size_t bytes)->char*{ char* p = ws + off; off += (bytes + 255) & ~(size_t)255; return p; };
  unsigned short* Wbuf = (unsigned short*)alloc((size_t)INTERD*HID*2);     // 32 MB
  unsigned short* hb   = (unsigned short*)alloc((size_t)NTOK*HID*2);       // 16 MB
  unsigned short* qkvb = (unsigned short*)alloc((size_t)NTOK*3*HID*2);     // 48 MB
  unsigned short* aob  = (unsigned short*)alloc((size_t)NTOK*HID*2);       // 16 MB
  float*          x1   = (float*)alloc((size_t)NTOK*HID*4);                // 32 MB
  float*          cosb = (float*)alloc((size_t)SEQL*64*4);
  float*          sinb = (float*)alloc((size_t)SEQL*64*4);
  unsigned short* gb   = qkvb;                // 64 MB overlay (qkvb+aob), dead after O-proj
  unsigned short* VT   = (unsigned short*)x1; // 16 MB overlay: x1 written only after attn
  if(ws_size < off){ k_sentinel<<<1,1,0,stream>>>(out); return; }

  k_ropetab<<<SEQL, 64, 0, stream>>>(cosb, sinb);

  // ---- attention sublayer ----
  k_rmsnorm<<<NTOK, 256, 0, stream>>>(x, anw, hb);
  k_cvt<<<HID*HID/1024, 256, 0, stream>>>(qw, Wbuf,             HID*HID/4);
  k_cvt<<<HID*HID/1024, 256, 0, stream>>>(kw, Wbuf +   HID*HID, HID*HID/4);
  k_cvt<<<HID*HID/1024, 256, 0, stream>>>(vw, Wbuf + 2*HID*HID, HID*HID/4);
  k_gemm<0><<<(NTOK/128)*(3*HID/128), 256, 0, stream>>>(hb, Wbuf, qkvb, nullptr, nullptr, NTOK, 3*HID, HID); // 1536 blk
  k_rope<<<(NTOK*NH*64)/256, 256, 0, stream>>>(qkvb,        3*HID, cosb, sinb, 0.08838834764831845f);
  k_rope<<<(NTOK*NH*64)/256, 256, 0, stream>>>(qkvb +  HID, 3*HID, cosb, sinb, 1.0f);
  k_transpose_v<<<NBATCH*NH*(SEQL/64), 256, 0, stream>>>(qkvb + 2*HID, 3*HID, VT);
  k_attn<<<(SEQL/64)*NBATCH*NH, 256, 0, stream>>>(qkvb, qkvb + HID, 3*HID, VT, aob);
  k_cvt<<<HID*HID/1024, 256, 0, stream>>>(ow, Wbuf, HID*HID/4);
  k_gemm<1><<<(NTOK/128)*(HID/128), 256, 0, stream>>>(aob, Wbuf, x1, x, nullptr, NTOK, HID, HID);            // 512 blk

  // ---- MLP sublayer ----
  k_rmsnorm<<<NTOK, 256, 0, stream>>>(x1, fnw, hb);
  k_cvt<<<INTERD*HID/1024, 256, 0, stream>>>(gw, Wbuf, INTERD*HID/4);
  k_gemm<0><<<(NTOK/128)*(INTERD/128), 256, 0, stream>>>(hb, Wbuf, gb, nullptr, nullptr, NTOK, INTERD, HID); // 2048 blk
  k_cvt<<<INTERD*HID/1024, 256, 0, stream>>>(uw, Wbuf, INTERD*HID/4);
  k_gemm<2><<<(NTOK/128)*(INTERD/128), 256, 0, stream>>>(hb, Wbuf, gb, nullptr, gb, NTOK, INTERD, HID);
  k_cvt<<<INTERD*HID/1024, 256, 0, stream>>>(dw, Wbuf, INTERD*HID/4);
  k_gemm<1><<<(NTOK/128)*(HID/128), 256, 0, stream>>>(gb, Wbuf, out, x1, nullptr, NTOK, HID, INTERD);        // 512 blk
}